// Round 5
// baseline (11164.243 us; speedup 1.0000x reference)
//
#include <hip/hip_runtime.h>
#include <math.h>

#define TT   96
#define SSS  128
#define DMM  512
#define DSS  256
#define BSS  512
#define NBLK 256
#define NTHR 512
#define DECAYF 0.6065306597126334f

#define AT_ADD(p, v) __hip_atomic_fetch_add((p), (v), __ATOMIC_RELAXED, __HIP_MEMORY_SCOPE_AGENT)
#define AT_ST(p, v)  __hip_atomic_store((p), (v), __ATOMIC_RELAXED, __HIP_MEMORY_SCOPE_AGENT)
#define AT_LD(p)     __hip_atomic_load((p), __ATOMIC_RELAXED, __HIP_MEMORY_SCOPE_AGENT)

// ---------------- workspace layout (float offsets) ----------------
static constexpr size_t OFS_KT    = 0;                        // K^T [96][256 d][512 key]
static constexpr size_t OFS_V     = 12582912;                 // [96][512 tok][256 d]
static constexpr size_t OFS_XD    = 25165824;                 // [96][512 tok][512 dm]
static constexpr size_t OFS_AT    = 50331648;                 // A^T  [256][256]
static constexpr size_t OFS_WQT   = 50397184;                 // Wq^T [256][256]
static constexpr size_t OFS_WOT   = 50462720;                 // Wo^T [256][256]
static constexpr size_t OFS_CT    = 50528256;                 // C^T  [256][512]
static constexpr size_t OFS_TP    = 50659328;                 // [3][256] LIF1 spike sums
static constexpr size_t OFS_TOP   = 50660096;                 // [3][512] LIF2 spike sums
static constexpr size_t OFS_FLAGS = 50661632;                 // int[96] (+pad)
static constexpr size_t OFS_ARR   = 50661760;                 // int arrival counter (+pad)
static constexpr size_t WS_FLOATS = 50661824;                 // 193.2 MiB (< proven 193.4)

// ---------------- fallback: zero the output (keeps capture non-empty) ----------------
extern "C" __global__ void __launch_bounds__(256)
zfill_kernel(float* __restrict__ out, int n) {
  int i = blockIdx.x * 256 + threadIdx.x;
  if (i < n) out[i] = 0.f;
}

// ---------------- flags: any(x_t > 0) ----------------
extern "C" __global__ void __launch_bounds__(256)
flags_kernel(const float* __restrict__ x, int* __restrict__ flags) {
  __shared__ int f;
  if (threadIdx.x == 0) f = 0;
  __syncthreads();
  int t = blockIdx.x;
  int any = 0;
  for (int b = 0; b < 4; ++b) {
    const float4* base = (const float4*)(x + ((size_t)(b * TT + t) * SSS) * DMM);
    for (int i = threadIdx.x; i < 16384; i += 256) {
      float4 v = base[i];
      any |= (v.x > 0.f) | (v.y > 0.f) | (v.z > 0.f) | (v.w > 0.f);
    }
  }
  if (any) atomicOr(&f, 1);
  __syncthreads();
  if (threadIdx.x == 0) flags[t] = f;
}

// ---------------- weight transposes ----------------
extern "C" __global__ void __launch_bounds__(256)
tr_kernel(const float* __restrict__ A, const float* __restrict__ Wq,
          const float* __restrict__ Wo, const float* __restrict__ C,
          float* __restrict__ ws) {
  __shared__ float tile[32][33];
  int b = blockIdx.x;
  const float* src; float* dst; int RS, CS, tb;
  if (b < 64)       { src = A;  dst = ws + OFS_AT;  RS = 256; CS = 256; tb = b; }
  else if (b < 128) { src = Wq; dst = ws + OFS_WQT; RS = 256; CS = 256; tb = b - 64; }
  else if (b < 192) { src = Wo; dst = ws + OFS_WOT; RS = 256; CS = 256; tb = b - 128; }
  else              { src = C;  dst = ws + OFS_CT;  RS = 512; CS = 256; tb = b - 192; }
  int tpr = CS / 32;
  int trr = tb / tpr, tcc = tb % tpr;
  int r0 = trr * 32, c0 = tcc * 32;
  int tx = threadIdx.x & 31, ty = threadIdx.x >> 5;
  #pragma unroll
  for (int j = 0; j < 4; ++j)
    tile[ty + j * 8][tx] = src[(size_t)(r0 + ty + j * 8) * CS + c0 + tx];
  __syncthreads();
  #pragma unroll
  for (int j = 0; j < 4; ++j)
    dst[(size_t)(c0 + ty + j * 8) * RS + r0 + tx] = tile[tx][ty + j * 8];
}

// ---------------- precompute K^T, V, XD ----------------
extern "C" __global__ void __launch_bounds__(256)
pre_kernel(const float* __restrict__ x,
           const float* __restrict__ Wk, const float* __restrict__ bk,
           const float* __restrict__ Wv, const float* __restrict__ bv,
           const float* __restrict__ D,  float* __restrict__ ws) {
  __shared__ float As[32 * 68];
  __shared__ float Bs[32 * 68];
  int bid = blockIdx.x;
  int nt = bid & 15, mt = bid >> 4;
  int row0 = mt * 64, col0 = nt * 64;
  int tid = threadIdx.x;
  int trd = tid & 15, tc = tid >> 4;
  float acc[4][4] = {};
  for (int kk = 0; kk < 512; kk += 32) {
    __syncthreads();
    { int m = tid >> 2, ks = (tid & 3) * 8;
      const float* src = x + (size_t)(row0 + m) * 512 + kk + ks;
      float4 a = *(const float4*)(src);
      float4 b = *(const float4*)(src + 4);
      As[(ks + 0) * 68 + m] = a.x; As[(ks + 1) * 68 + m] = a.y;
      As[(ks + 2) * 68 + m] = a.z; As[(ks + 3) * 68 + m] = a.w;
      As[(ks + 4) * 68 + m] = b.x; As[(ks + 5) * 68 + m] = b.y;
      As[(ks + 6) * 68 + m] = b.z; As[(ks + 7) * 68 + m] = b.w; }
    { int n = tid >> 2, ks = (tid & 3) * 8;
      int gc = col0 + n;
      const float* wr = (gc < 256) ? (Wk + (size_t)gc * 512)
                      : (gc < 512) ? (Wv + (size_t)(gc - 256) * 512)
                                   : (D  + (size_t)(gc - 512) * 512);
      const float* src = wr + kk + ks;
      float4 a = *(const float4*)(src);
      float4 b = *(const float4*)(src + 4);
      Bs[(ks + 0) * 68 + n] = a.x; Bs[(ks + 1) * 68 + n] = a.y;
      Bs[(ks + 2) * 68 + n] = a.z; Bs[(ks + 3) * 68 + n] = a.w;
      Bs[(ks + 4) * 68 + n] = b.x; Bs[(ks + 5) * 68 + n] = b.y;
      Bs[(ks + 6) * 68 + n] = b.z; Bs[(ks + 7) * 68 + n] = b.w; }
    __syncthreads();
    #pragma unroll 8
    for (int k = 0; k < 32; ++k) {
      float4 a4 = *(const float4*)(As + k * 68 + trd * 4);
      float4 b4 = *(const float4*)(Bs + k * 68 + tc * 4);
      float am[4] = {a4.x, a4.y, a4.z, a4.w};
      float bn[4] = {b4.x, b4.y, b4.z, b4.w};
      #pragma unroll
      for (int i = 0; i < 4; ++i)
        #pragma unroll
        for (int j = 0; j < 4; ++j)
          acc[i][j] = fmaf(am[i], bn[j], acc[i][j]);
    }
  }
  for (int i = 0; i < 4; ++i) {
    int g = row0 + trd * 4 + i;
    int b = g / 12288, r1 = g % 12288;
    int t_ = r1 / 128, s_ = r1 % 128;
    int tokidx = b * SSS + s_;
    size_t drow = (size_t)t_ * BSS + tokidx;
    int gc0 = col0 + tc * 4;
    float4 o = make_float4(acc[i][0], acc[i][1], acc[i][2], acc[i][3]);
    if (gc0 < 256) {
      // K stored TRANSPOSED: KT[t][c][tok]
      float vals[4] = {o.x + bk[gc0], o.y + bk[gc0 + 1], o.z + bk[gc0 + 2], o.w + bk[gc0 + 3]};
      #pragma unroll
      for (int j = 0; j < 4; ++j)
        ws[OFS_KT + (size_t)t_ * 131072 + (size_t)(gc0 + j) * 512 + tokidx] = vals[j];
    } else if (gc0 < 512) {
      int c = gc0 - 256;
      o.x += bv[c]; o.y += bv[c + 1]; o.z += bv[c + 2]; o.w += bv[c + 3];
      *(float4*)(ws + OFS_V + drow * DSS + c) = o;
    } else {
      *(float4*)(ws + OFS_XD + drow * DMM + (gc0 - 512)) = o;
    }
  }
}

// ---------------- sequential recurrence: split arrive/wait, 2 tokens/block ----------------
extern "C" __global__ void __launch_bounds__(NTHR)
seq_kernel(const float* __restrict__ bq, const float* __restrict__ bo,
           float* __restrict__ ws, float* __restrict__ out) {
  __shared__ float part[4096];      // AV partials (4096) / gi partials (2048)
  __shared__ float sw[8 * 520];     // scores [2 tok x 4 head][520]
  __shared__ float sh[512];         // h spikes [2][256]
  __shared__ float ssv[512];        // LIF1 vmem
  __shared__ float sst[512];        // st
  __shared__ float squ[1024];       // sqv [2][256] | sav [2][256] ; alias sou [2][512]
  __shared__ float sov[1024];       // LIF2 vmem [2][512]
  __shared__ float sts[DSS];
  __shared__ float sto[DMM];
  __shared__ int   acts[512];       // active-k lists [2][256]
  __shared__ int   nact2[2];
  __shared__ int   bok;

  float* sqv = squ;
  float* sav = squ + 512;
  float* sou = squ;                 // [2][512] alias

  const float* At  = ws + OFS_AT;
  const float* Wqt = ws + OFS_WQT;
  const float* Wot = ws + OFS_WOT;
  const float* Ct  = ws + OFS_CT;
  const float* XD  = ws + OFS_XD;
  float* tp  = ws + OFS_TP;
  float* top = ws + OFS_TOP;
  const int* flags = (const int*)(ws + OFS_FLAGS);
  int* arr = (int*)(ws + OFS_ARR);

  const int tid = threadIdx.x;
  const int bid = blockIdx.x;

  // ---- init (global partial slots + arr pre-zeroed by host memset) ----
  sh[tid] = 0.f;
  ssv[tid] = 0.f;
  sov[tid] = 0.f; sov[512 + tid] = 0.f;
  if (tid < 256) sts[tid] = 1.f;
  sto[tid] = 1.f;
  if (tid == 0) bok = 1;
  __syncthreads();

  for (int t = 0; t < TT; ++t) {
    const int fl = flags[t];

    // ===== P1: active-k compaction of h (ascending => exact vs dense) =====
    if (tid < 128) {
      int r = tid >> 6, lane = tid & 63;
      int base = 0;
      for (int seg = 0; seg < 4; ++seg) {
        int k = seg * 64 + lane;
        bool p = sh[r * 256 + k] > 0.5f;
        unsigned long long m = __ballot(p);
        int pre = __popcll(m & ((1ull << lane) - 1ull));
        if (p) acts[r * 256 + base + pre] = k;
        base += __popcll(m);
      }
      if (lane == 0) nact2[r] = base;
    }
    __syncthreads();

    // ===== P2: st = h@A^T ; q = h@Wq^T + bq (sparse gathers, coalesced) =====
    {
      int r = tid >> 8, c = tid & 255;
      int n = nact2[r];
      const int* al = acts + r * 256;
      float aS = 0.f, aQ = 0.f;
      if (fl) {
        for (int i = 0; i < n; ++i) {
          int k = al[i];
          aS += At[(size_t)k * 256 + c];
          aQ += Wqt[(size_t)k * 256 + c];
        }
        sqv[r * 256 + c] = aQ + bq[c];
      } else {
        for (int i = 0; i < n; ++i) aS += At[(size_t)(al[i]) * 256 + c];
      }
      sst[r * 256 + c] = aS;
    }
    __syncthreads();

    if (fl) {
      // ===== P3: scores from K^T — thread=key, fully coalesced columns =====
      {
        const float* ktb = ws + OFS_KT + (size_t)t * 131072 + tid;
        #pragma unroll
        for (int hd = 0; hd < 4; ++hd) {
          float a0 = 0.f, a1 = 0.f;
          #pragma unroll 16
          for (int j = 0; j < 64; ++j) {
            float kv = ktb[(size_t)(hd * 64 + j) * 512];
            a0 = fmaf(kv, sqv[hd * 64 + j], a0);
            a1 = fmaf(kv, sqv[256 + hd * 64 + j], a1);
          }
          sw[hd * 520 + tid]       = a0 * 0.125f;
          sw[(4 + hd) * 520 + tid] = a1 * 0.125f;
        }
      }
      __syncthreads();

      // ===== P4: softmax (one wave per (tok,head) row of 512) =====
      {
        int w = tid >> 6, lane = tid & 63;
        float* row = sw + w * 520;
        float4 v0 = ((const float4*)row)[lane * 2];
        float4 v1 = ((const float4*)row)[lane * 2 + 1];
        float m = fmaxf(fmaxf(fmaxf(v0.x, v0.y), fmaxf(v0.z, v0.w)),
                        fmaxf(fmaxf(v1.x, v1.y), fmaxf(v1.z, v1.w)));
        for (int o = 32; o > 0; o >>= 1) m = fmaxf(m, __shfl_xor(m, o));
        v0.x = expf(v0.x - m); v0.y = expf(v0.y - m); v0.z = expf(v0.z - m); v0.w = expf(v0.w - m);
        v1.x = expf(v1.x - m); v1.y = expf(v1.y - m); v1.z = expf(v1.z - m); v1.w = expf(v1.w - m);
        float s = v0.x + v0.y + v0.z + v0.w + v1.x + v1.y + v1.z + v1.w;
        for (int o = 32; o > 0; o >>= 1) s += __shfl_xor(s, o);
        float inv = 1.f / s;
        v0.x *= inv; v0.y *= inv; v0.z *= inv; v0.w *= inv;
        v1.x *= inv; v1.y *= inv; v1.z *= inv; v1.w *= inv;
        ((float4*)row)[lane * 2] = v0; ((float4*)row)[lane * 2 + 1] = v1;
      }
      __syncthreads();

      // ===== P5: AV (V coalesced; 8-way key split) =====
      {
        int kg = tid >> 6, dq = tid & 63, hd = dq >> 4;
        const float4* vp = (const float4*)(ws + OFS_V + (size_t)t * 131072) + dq;
        float4 a0 = make_float4(0.f, 0.f, 0.f, 0.f);
        float4 a1 = make_float4(0.f, 0.f, 0.f, 0.f);
        for (int i = 0; i < 64; ++i) {
          int key = kg * 64 + i;
          float4 v = vp[(size_t)key * 64];
          float w0 = sw[hd * 520 + key];
          float w1 = sw[(4 + hd) * 520 + key];
          a0.x = fmaf(w0, v.x, a0.x); a0.y = fmaf(w0, v.y, a0.y);
          a0.z = fmaf(w0, v.z, a0.z); a0.w = fmaf(w0, v.w, a0.w);
          a1.x = fmaf(w1, v.x, a1.x); a1.y = fmaf(w1, v.y, a1.y);
          a1.z = fmaf(w1, v.z, a1.z); a1.w = fmaf(w1, v.w, a1.w);
        }
        *(float4*)(part + (kg * 2 + 0) * 256 + dq * 4) = a0;
        *(float4*)(part + (kg * 2 + 1) * 256 + dq * 4) = a1;
      }
      __syncthreads();
      {
        int r = tid >> 8, d = tid & 255;
        float s = 0.f;
        #pragma unroll
        for (int kg = 0; kg < 8; ++kg) s += part[(kg * 2 + r) * 256 + d];
        sav[r * 256 + d] = s;
      }
      __syncthreads();
    }

    // ===== P6a: gi = av@Wo^T + bo (before the wait — overlaps sync latency) =====
    float gi = 0.f;
    if (fl) {
      int r6 = tid >> 8, ks4 = (tid >> 6) & 3, cq = tid & 63;
      float4 a = make_float4(0.f, 0.f, 0.f, 0.f);
      const float* avr = sav + r6 * 256;
      for (int k = ks4 * 64; k < ks4 * 64 + 64; ++k) {
        float avv = avr[k];
        float4 wo = *(const float4*)(Wot + (size_t)k * 256 + cq * 4);
        a.x = fmaf(avv, wo.x, a.x); a.y = fmaf(avv, wo.y, a.y);
        a.z = fmaf(avv, wo.z, a.z); a.w = fmaf(avv, wo.w, a.w);
      }
      *(float4*)(part + ((r6 * 4 + ks4) * 64 + cq) * 4) = a;
      __syncthreads();
      int r = tid >> 8, c = tid & 255;
      gi = (((part[(r * 4 + 0) * 256 + c]
            + part[(r * 4 + 1) * 256 + c])
            + part[(r * 4 + 2) * 256 + c])
            + part[(r * 4 + 3) * 256 + c]) + bo[c];
    }

    // ===== WAIT: all blocks arrived step t-1 => threshold sums final =====
    __syncthreads();
    if (tid == 0 && t > 0 && bok) {
      int target = t * NBLK;
      int spin = 0;
      while (AT_LD(arr) < target) {
        if (spin < 256) __builtin_amdgcn_s_sleep(1);
        else            __builtin_amdgcn_s_sleep(16);
        if (++spin > (1 << 21)) { bok = 0; break; }
      }
    }
    __syncthreads();
    if (t > 0) {
      int ps = (t - 1) % 3;
      if (tid < 256) {
        float s = AT_LD(tp + ps * 256 + tid);
        sts[tid] += 0.1f * (s * (1.f / 512.f) - 0.1f);
      }
      if (flags[t - 1]) {
        float s = AT_LD(top + ps * 512 + tid);
        sto[tid] += 0.1f * (s * (1.f / 512.f) - 0.1f);
      }
      if (bid == 0) {                    // just-in-time zero of slot for step t+1
        int zs = (t + 1) % 3;
        if (tid < 256) AT_ST(tp + zs * 256 + tid, 0.f);
        AT_ST(top + zs * 512 + tid, 0.f);
      }
      __syncthreads();
    }

    // ===== P6b: LIF1 ; publish tpart =====
    {
      int r = tid >> 8, c = tid & 255;
      float in1 = sst[r * 256 + c] + gi;
      float vp = ssv[r * 256 + c] * DECAYF + in1;
      float sp = (vp >= sts[c]) ? 1.f : 0.f;
      ssv[r * 256 + c] = vp * (1.f - sp);
      sh[r * 256 + c] = sp;
    }
    __syncthreads();
    if (tid < 256) AT_ADD(tp + (t % 3) * 256 + tid, sh[tid] + sh[256 + tid]);

    // ===== P7: up = h2@C^T + XD ; LIF2 ; out ; publish topart =====
    if (fl) {
      if (tid < 128) {
        int r = tid >> 6, lane = tid & 63;
        int base = 0;
        for (int seg = 0; seg < 4; ++seg) {
          int k = seg * 64 + lane;
          bool p = sh[r * 256 + k] > 0.5f;
          unsigned long long m = __ballot(p);
          int pre = __popcll(m & ((1ull << lane) - 1ull));
          if (p) acts[r * 256 + base + pre] = k;
          base += __popcll(m);
        }
        if (lane == 0) nact2[r] = base;
      }
      __syncthreads();
      {
        int r = tid >> 8, c2 = tid & 255, m0 = c2 * 2;
        int grow = bid * 2 + r;
        int n = nact2[r];
        const int* al = acts + r * 256;
        float a0 = 0.f, a1 = 0.f;
        for (int i = 0; i < n; ++i) {
          int k = al[i];
          float2 cv = *(const float2*)(Ct + (size_t)k * 512 + m0);
          a0 += cv.x; a1 += cv.y;
        }
        float2 xd = *(const float2*)(XD + ((size_t)t * 512 + grow) * 512 + m0);
        float up0 = a0 + xd.x, up1 = a1 + xd.y;
        float vp0 = sov[r * 512 + m0] * DECAYF + up0;
        float vp1 = sov[r * 512 + m0 + 1] * DECAYF + up1;
        float s0 = (vp0 >= sto[m0]) ? 1.f : 0.f;
        float s1 = (vp1 >= sto[m0 + 1]) ? 1.f : 0.f;
        sov[r * 512 + m0] = vp0 * (1.f - s0);
        sov[r * 512 + m0 + 1] = vp1 * (1.f - s1);
        sou[r * 512 + m0] = s0; sou[r * 512 + m0 + 1] = s1;
        int b = grow >> 7, sI = grow & 127;
        float2 o2; o2.x = s0; o2.y = s1;
        *(float2*)(out + (((size_t)b * TT + t) * SSS + sI) * DMM + m0) = o2;
      }
      __syncthreads();
      AT_ADD(top + (t % 3) * 512 + tid, sou[tid] + sou[512 + tid]);
    } else {
      int r = tid >> 8, c2 = tid & 255, m0 = c2 * 2;
      int grow = bid * 2 + r;
      int b = grow >> 7, sI = grow & 127;
      float2 z; z.x = 0.f; z.y = 0.f;
      *(float2*)(out + (((size_t)b * TT + t) * SSS + sI) * DMM + m0) = z;
    }

    // ===== ARRIVE (monotonic counter; partials drained first) =====
    __syncthreads();
    if (tid == 0) {
      asm volatile("s_waitcnt vmcnt(0)" ::: "memory");
      AT_ADD(arr, 1);
    }
  }
}

// ---------------- host ----------------
extern "C" void kernel_launch(void* const* d_in, const int* in_sizes, int n_in,
                              void* d_out, int out_size, void* d_ws, size_t ws_size,
                              hipStream_t stream) {
  const float* x  = (const float*)d_in[0];
  const float* Aw = (const float*)d_in[1];
  const float* Cw = (const float*)d_in[2];
  const float* Dw = (const float*)d_in[3];
  const float* Wq = (const float*)d_in[4];
  const float* bq = (const float*)d_in[5];
  const float* Wk = (const float*)d_in[6];
  const float* bk = (const float*)d_in[7];
  const float* Wv = (const float*)d_in[8];
  const float* bv = (const float*)d_in[9];
  const float* Wo = (const float*)d_in[10];
  const float* bo = (const float*)d_in[11];
  float* ws  = (float*)d_ws;
  float* out = (float*)d_out;

  if (ws_size < WS_FLOATS * sizeof(float)) {
    hipLaunchKernelGGL(zfill_kernel, dim3((out_size + 255) / 256), dim3(256), 0, stream,
                       out, out_size);
    return;
  }

  // zero partial slots + flags pad + arrival counter (floats 0.0f == 0 bits)
  hipMemsetAsync((void*)(ws + OFS_TP), 0, (WS_FLOATS - OFS_TP) * sizeof(float), stream);
  hipLaunchKernelGGL(flags_kernel, dim3(TT), dim3(256), 0, stream, x, (int*)(ws + OFS_FLAGS));
  hipLaunchKernelGGL(tr_kernel, dim3(320), dim3(256), 0, stream, Aw, Wq, Wo, Cw, ws);
  hipLaunchKernelGGL(pre_kernel, dim3(12288), dim3(256), 0, stream, x, Wk, bk, Wv, bv, Dw, ws);

  void* kargs[] = { (void*)&bq, (void*)&bo, (void*)&ws, (void*)&out };
  hipLaunchCooperativeKernel((void*)seq_kernel, dim3(NBLK), dim3(NTHR), kargs, 0, stream);
}

// Round 6
// 8293.099 us; speedup vs baseline: 1.3462x; 1.3462x over previous
//
#include <hip/hip_runtime.h>
#include <math.h>

#define TT   96
#define SSS  128
#define DMM  512
#define DSS  256
#define BSS  512
#define NBLK 256
#define NTHR 1024
#define DECAYF 0.6065306597126334f

#define AT_ADD(p, v) __hip_atomic_fetch_add((p), (v), __ATOMIC_RELAXED, __HIP_MEMORY_SCOPE_AGENT)
#define AT_ST(p, v)  __hip_atomic_store((p), (v), __ATOMIC_RELAXED, __HIP_MEMORY_SCOPE_AGENT)
#define AT_LD(p)     __hip_atomic_load((p), __ATOMIC_RELAXED, __HIP_MEMORY_SCOPE_AGENT)

// ---------------- workspace layout (float offsets) ----------------
static constexpr size_t OFS_KT    = 0;                        // K^T [96][256 d][512 key]
static constexpr size_t OFS_V     = 12582912;                 // [96][512 tok][256 d]
static constexpr size_t OFS_XD    = 25165824;                 // [96][512 tok][512 dm]
static constexpr size_t OFS_AT    = 50331648;                 // A^T  [256][256]
static constexpr size_t OFS_WQT   = 50397184;                 // Wq^T [256][256]
static constexpr size_t OFS_WOT   = 50462720;                 // Wo^T [256][256]
static constexpr size_t OFS_CT    = 50528256;                 // C^T  [256][512]
static constexpr size_t OFS_TP    = 50659328;                 // [3][256] LIF1 spike sums
static constexpr size_t OFS_TOP   = 50660096;                 // [3][512] LIF2 spike sums
static constexpr size_t OFS_FLAGS = 50661632;                 // int[96] (+pad)
static constexpr size_t OFS_ARR   = 50661760;                 // int arrival counter (+pad)
static constexpr size_t WS_FLOATS = 50661824;                 // 193.2 MiB

// ---------------- fallback: zero the output (keeps capture non-empty) ----------------
extern "C" __global__ void __launch_bounds__(256)
zfill_kernel(float* __restrict__ out, int n) {
  int i = blockIdx.x * 256 + threadIdx.x;
  if (i < n) out[i] = 0.f;
}

// ---------------- flags: any(x_t > 0) ----------------
extern "C" __global__ void __launch_bounds__(256)
flags_kernel(const float* __restrict__ x, int* __restrict__ flags) {
  __shared__ int f;
  if (threadIdx.x == 0) f = 0;
  __syncthreads();
  int t = blockIdx.x;
  int any = 0;
  for (int b = 0; b < 4; ++b) {
    const float4* base = (const float4*)(x + ((size_t)(b * TT + t) * SSS) * DMM);
    for (int i = threadIdx.x; i < 16384; i += 256) {
      float4 v = base[i];
      any |= (v.x > 0.f) | (v.y > 0.f) | (v.z > 0.f) | (v.w > 0.f);
    }
  }
  if (any) atomicOr(&f, 1);
  __syncthreads();
  if (threadIdx.x == 0) flags[t] = f;
}

// ---------------- weight transposes ----------------
extern "C" __global__ void __launch_bounds__(256)
tr_kernel(const float* __restrict__ A, const float* __restrict__ Wq,
          const float* __restrict__ Wo, const float* __restrict__ C,
          float* __restrict__ ws) {
  __shared__ float tile[32][33];
  int b = blockIdx.x;
  const float* src; float* dst; int RS, CS, tb;
  if (b < 64)       { src = A;  dst = ws + OFS_AT;  RS = 256; CS = 256; tb = b; }
  else if (b < 128) { src = Wq; dst = ws + OFS_WQT; RS = 256; CS = 256; tb = b - 64; }
  else if (b < 192) { src = Wo; dst = ws + OFS_WOT; RS = 256; CS = 256; tb = b - 128; }
  else              { src = C;  dst = ws + OFS_CT;  RS = 512; CS = 256; tb = b - 192; }
  int tpr = CS / 32;
  int trr = tb / tpr, tcc = tb % tpr;
  int r0 = trr * 32, c0 = tcc * 32;
  int tx = threadIdx.x & 31, ty = threadIdx.x >> 5;
  #pragma unroll
  for (int j = 0; j < 4; ++j)
    tile[ty + j * 8][tx] = src[(size_t)(r0 + ty + j * 8) * CS + c0 + tx];
  __syncthreads();
  #pragma unroll
  for (int j = 0; j < 4; ++j)
    dst[(size_t)(c0 + ty + j * 8) * RS + r0 + tx] = tile[tx][ty + j * 8];
}

// ---------------- precompute K^T, V, XD ----------------
extern "C" __global__ void __launch_bounds__(256)
pre_kernel(const float* __restrict__ x,
           const float* __restrict__ Wk, const float* __restrict__ bk,
           const float* __restrict__ Wv, const float* __restrict__ bv,
           const float* __restrict__ D,  float* __restrict__ ws) {
  __shared__ float As[32 * 68];
  __shared__ float Bs[32 * 68];
  int bid = blockIdx.x;
  int nt = bid & 15, mt = bid >> 4;
  int row0 = mt * 64, col0 = nt * 64;
  int tid = threadIdx.x;
  int trd = tid & 15, tc = tid >> 4;
  float acc[4][4] = {};
  for (int kk = 0; kk < 512; kk += 32) {
    __syncthreads();
    { int m = tid >> 2, ks = (tid & 3) * 8;
      const float* src = x + (size_t)(row0 + m) * 512 + kk + ks;
      float4 a = *(const float4*)(src);
      float4 b = *(const float4*)(src + 4);
      As[(ks + 0) * 68 + m] = a.x; As[(ks + 1) * 68 + m] = a.y;
      As[(ks + 2) * 68 + m] = a.z; As[(ks + 3) * 68 + m] = a.w;
      As[(ks + 4) * 68 + m] = b.x; As[(ks + 5) * 68 + m] = b.y;
      As[(ks + 6) * 68 + m] = b.z; As[(ks + 7) * 68 + m] = b.w; }
    { int n = tid >> 2, ks = (tid & 3) * 8;
      int gc = col0 + n;
      const float* wr = (gc < 256) ? (Wk + (size_t)gc * 512)
                      : (gc < 512) ? (Wv + (size_t)(gc - 256) * 512)
                                   : (D  + (size_t)(gc - 512) * 512);
      const float* src = wr + kk + ks;
      float4 a = *(const float4*)(src);
      float4 b = *(const float4*)(src + 4);
      Bs[(ks + 0) * 68 + n] = a.x; Bs[(ks + 1) * 68 + n] = a.y;
      Bs[(ks + 2) * 68 + n] = a.z; Bs[(ks + 3) * 68 + n] = a.w;
      Bs[(ks + 4) * 68 + n] = b.x; Bs[(ks + 5) * 68 + n] = b.y;
      Bs[(ks + 6) * 68 + n] = b.z; Bs[(ks + 7) * 68 + n] = b.w; }
    __syncthreads();
    #pragma unroll 8
    for (int k = 0; k < 32; ++k) {
      float4 a4 = *(const float4*)(As + k * 68 + trd * 4);
      float4 b4 = *(const float4*)(Bs + k * 68 + tc * 4);
      float am[4] = {a4.x, a4.y, a4.z, a4.w};
      float bn[4] = {b4.x, b4.y, b4.z, b4.w};
      #pragma unroll
      for (int i = 0; i < 4; ++i)
        #pragma unroll
        for (int j = 0; j < 4; ++j)
          acc[i][j] = fmaf(am[i], bn[j], acc[i][j]);
    }
  }
  for (int i = 0; i < 4; ++i) {
    int g = row0 + trd * 4 + i;
    int b = g / 12288, r1 = g % 12288;
    int t_ = r1 / 128, s_ = r1 % 128;
    int tokidx = b * SSS + s_;
    size_t drow = (size_t)t_ * BSS + tokidx;
    int gc0 = col0 + tc * 4;
    float4 o = make_float4(acc[i][0], acc[i][1], acc[i][2], acc[i][3]);
    if (gc0 < 256) {
      float vals[4] = {o.x + bk[gc0], o.y + bk[gc0 + 1], o.z + bk[gc0 + 2], o.w + bk[gc0 + 3]};
      #pragma unroll
      for (int j = 0; j < 4; ++j)
        ws[OFS_KT + (size_t)t_ * 131072 + (size_t)(gc0 + j) * 512 + tokidx] = vals[j];
    } else if (gc0 < 512) {
      int c = gc0 - 256;
      o.x += bv[c]; o.y += bv[c + 1]; o.z += bv[c + 2]; o.w += bv[c + 3];
      *(float4*)(ws + OFS_V + drow * DSS + c) = o;
    } else {
      *(float4*)(ws + OFS_XD + drow * DMM + (gc0 - 512)) = o;
    }
  }
}

// ---------------- sequential recurrence: prefetch + 16 waves/CU + arrive/wait ----------------
extern "C" __global__ void __launch_bounds__(NTHR, 4)
seq_kernel(const float* __restrict__ bq, const float* __restrict__ bo,
           float* __restrict__ ws, float* __restrict__ out) {
  __shared__ float part[4096];
  __shared__ float sw[8 * 520];     // scores [2 tok x 4 head][520]
  __shared__ float sh[512];
  __shared__ float ssv[512];
  __shared__ float sst[512];
  __shared__ float squ[1024];       // sqv [2][256] | sav [2][256] ; alias sou [2][512]
  __shared__ float sov[1024];
  __shared__ float sts[DSS];
  __shared__ float sto[DMM];
  __shared__ int   acts[512];
  __shared__ int   nact2[2];
  __shared__ int   bok;

  float* sqv = squ;
  float* sav = squ + 512;
  float* sou = squ;

  const float* At  = ws + OFS_AT;
  const float* Wqt = ws + OFS_WQT;
  const float* Wot = ws + OFS_WOT;
  const float* Ct  = ws + OFS_CT;
  const float* XD  = ws + OFS_XD;
  float* tp  = ws + OFS_TP;
  float* top = ws + OFS_TOP;
  const int* flags = (const int*)(ws + OFS_FLAGS);
  int* arr = (int*)(ws + OFS_ARR);

  const int tid = threadIdx.x;
  const int bid = blockIdx.x;

  if (tid < 512) { sh[tid] = 0.f; ssv[tid] = 0.f; sto[tid] = 1.f; }
  sov[tid] = 0.f;
  if (tid < 256) sts[tid] = 1.f;
  if (tid == 0) bok = 1;
  __syncthreads();

  for (int t = 0; t < TT; ++t) {
    const int fl = flags[t];

    // ===== P1: active-k compaction of h =====
    if (tid < 128) {
      int r = tid >> 6, lane = tid & 63;
      int base = 0;
      for (int seg = 0; seg < 4; ++seg) {
        int k = seg * 64 + lane;
        bool p = sh[r * 256 + k] > 0.5f;
        unsigned long long m = __ballot(p);
        int pre = __popcll(m & ((1ull << lane) - 1ull));
        if (p) acts[r * 256 + base + pre] = k;
        base += __popcll(m);
      }
      if (lane == 0) nact2[r] = base;
    }
    __syncthreads();

    // ===== P2: st / q sparse gathers, split-k halves over 1024 threads =====
    {
      int r = tid >> 9, half = (tid >> 8) & 1, c = tid & 255;
      int n = nact2[r];
      int n2 = n >> 1;
      int i0 = half ? n2 : 0;
      int i1 = half ? n : n2;
      const int* al = acts + r * 256;
      float aS = 0.f, aQ = 0.f;
      if (fl) {
        for (int i = i0; i < i1; ++i) {
          int k = al[i];
          aS += At[(size_t)k * 256 + c];
          aQ += Wqt[(size_t)k * 256 + c];
        }
      } else {
        for (int i = i0; i < i1; ++i) aS += At[(size_t)(al[i]) * 256 + c];
      }
      part[tid] = aS;
      part[1024 + tid] = aQ;
    }
    __syncthreads();
    if (tid < 512) {
      int r = tid >> 8, c = tid & 255;
      sst[tid] = part[r * 512 + c] + part[r * 512 + 256 + c];
      if (fl) sqv[tid] = part[1024 + r * 512 + c] + part[1024 + r * 512 + 256 + c] + bq[c];
    }

    // ===== PREFETCH step t+1 working set into this XCD's L2 =====
    if (t + 1 < TT) {
      int slot = bid >> 3;                 // %8 XCD round-robin -> 32 slots per XCD
      size_t pfb = (slot < 16)
        ? (OFS_KT + (size_t)(t + 1) * 131072 + (size_t)slot * 8192)
        : (OFS_V  + (size_t)(t + 1) * 131072 + (size_t)(slot - 16) * 8192);
      const float* pf = ws + pfb;
      #pragma unroll
      for (int i = 0; i < 8; ++i) {
        float v = pf[i * 1024 + tid];
        asm volatile("" :: "v"(v));        // keep load alive (no DCE)
      }
      int pr = tid >> 9, pc = tid & 511;
      float xv = XD[((size_t)(t + 1) * 512 + bid * 2 + pr) * 512 + pc];
      asm volatile("" :: "v"(xv));
    }
    __syncthreads();

    if (fl) {
      // ===== P3: scores from K^T — thread=(head-pair,key), coalesced =====
      {
        int hp = tid >> 9, key = tid & 511;
        const float* ktb = ws + OFS_KT + (size_t)t * 131072 + key;
        #pragma unroll
        for (int hh = 0; hh < 2; ++hh) {
          int hd = hp * 2 + hh;
          float a0 = 0.f, a1 = 0.f;
          #pragma unroll 16
          for (int j = 0; j < 64; ++j) {
            float kv = ktb[(size_t)(hd * 64 + j) * 512];
            a0 = fmaf(kv, sqv[hd * 64 + j], a0);
            a1 = fmaf(kv, sqv[256 + hd * 64 + j], a1);
          }
          sw[hd * 520 + key]       = a0 * 0.125f;
          sw[(4 + hd) * 520 + key] = a1 * 0.125f;
        }
      }
      __syncthreads();

      // ===== P4: softmax (8 waves, one per (tok,head)) =====
      if (tid < 512) {
        int w = tid >> 6, lane = tid & 63;
        float* row = sw + w * 520;
        float4 v0 = ((const float4*)row)[lane * 2];
        float4 v1 = ((const float4*)row)[lane * 2 + 1];
        float m = fmaxf(fmaxf(fmaxf(v0.x, v0.y), fmaxf(v0.z, v0.w)),
                        fmaxf(fmaxf(v1.x, v1.y), fmaxf(v1.z, v1.w)));
        for (int o = 32; o > 0; o >>= 1) m = fmaxf(m, __shfl_xor(m, o));
        v0.x = expf(v0.x - m); v0.y = expf(v0.y - m); v0.z = expf(v0.z - m); v0.w = expf(v0.w - m);
        v1.x = expf(v1.x - m); v1.y = expf(v1.y - m); v1.z = expf(v1.z - m); v1.w = expf(v1.w - m);
        float s = v0.x + v0.y + v0.z + v0.w + v1.x + v1.y + v1.z + v1.w;
        for (int o = 32; o > 0; o >>= 1) s += __shfl_xor(s, o);
        float inv = 1.f / s;
        v0.x *= inv; v0.y *= inv; v0.z *= inv; v0.w *= inv;
        v1.x *= inv; v1.y *= inv; v1.z *= inv; v1.w *= inv;
        ((float4*)row)[lane * 2] = v0; ((float4*)row)[lane * 2 + 1] = v1;
      }
      __syncthreads();

      // ===== P5: AV — thread=(key-group, tok, d4); 8-way key split =====
      {
        int kg = tid >> 7, r5 = (tid >> 6) & 1, dq = tid & 63, hd = dq >> 4;
        const float4* vp = (const float4*)(ws + OFS_V + (size_t)t * 131072) + dq;
        const float* swr = sw + (r5 * 4 + hd) * 520;
        float4 a = make_float4(0.f, 0.f, 0.f, 0.f);
        for (int i = 0; i < 64; ++i) {
          int key = kg * 64 + i;
          float4 v = vp[(size_t)key * 64];
          float w0 = swr[key];
          a.x = fmaf(w0, v.x, a.x); a.y = fmaf(w0, v.y, a.y);
          a.z = fmaf(w0, v.z, a.z); a.w = fmaf(w0, v.w, a.w);
        }
        *(float4*)(part + (kg * 2 + r5) * 256 + dq * 4) = a;
      }
      __syncthreads();
      if (tid < 512) {
        int r = tid >> 8, d = tid & 255;
        float s = 0.f;
        #pragma unroll
        for (int kg = 0; kg < 8; ++kg) s += part[(kg * 2 + r) * 256 + d];
        sav[r * 256 + d] = s;
      }
      __syncthreads();
    }

    // ===== P6a: gi = av@Wo^T + bo (8-way k-split; before the wait) =====
    float gi = 0.f;
    if (fl) {
      int r6 = tid >> 9, ks8 = (tid >> 6) & 7, cq = tid & 63;
      float4 a = make_float4(0.f, 0.f, 0.f, 0.f);
      const float* avr = sav + r6 * 256;
      for (int k = ks8 * 32; k < ks8 * 32 + 32; ++k) {
        float avv = avr[k];
        float4 wo = *(const float4*)(Wot + (size_t)k * 256 + cq * 4);
        a.x = fmaf(avv, wo.x, a.x); a.y = fmaf(avv, wo.y, a.y);
        a.z = fmaf(avv, wo.z, a.z); a.w = fmaf(avv, wo.w, a.w);
      }
      *(float4*)(part + ((r6 * 8 + ks8) * 64 + cq) * 4) = a;
      __syncthreads();
      if (tid < 512) {
        int r = tid >> 8, c = tid & 255;
        float s = 0.f;
        #pragma unroll
        for (int j = 0; j < 8; ++j) s += part[(r * 8 + j) * 256 + c];
        gi = s + bo[c];
      }
    }

    // ===== WAIT: all blocks arrived step t-1 -> threshold sums final =====
    __syncthreads();
    if (tid == 0 && t > 0 && bok) {
      int target = t * NBLK;
      int spin = 0;
      while (AT_LD(arr) < target) {
        if (spin < 256) __builtin_amdgcn_s_sleep(1);
        else            __builtin_amdgcn_s_sleep(8);
        if (++spin > (1 << 21)) { bok = 0; break; }
      }
    }
    __syncthreads();
    if (t > 0) {
      int ps = (t - 1) % 3;
      if (tid < 256) {
        float s = AT_LD(tp + ps * 256 + tid);
        sts[tid] += 0.1f * (s * (1.f / 512.f) - 0.1f);
      }
      if (tid < 512 && flags[t - 1]) {
        float s = AT_LD(top + ps * 512 + tid);
        sto[tid] += 0.1f * (s * (1.f / 512.f) - 0.1f);
      }
      if (bid == 0) {
        int zs = (t + 1) % 3;
        if (tid < 256) AT_ST(tp + zs * 256 + tid, 0.f);
        if (tid < 512) AT_ST(top + zs * 512 + tid, 0.f);
      }
      __syncthreads();
    }

    // ===== P6b: LIF1 ; publish tp =====
    if (tid < 512) {
      int c = tid & 255;
      float in1 = sst[tid] + gi;
      float vp = ssv[tid] * DECAYF + in1;
      float sp = (vp >= sts[c]) ? 1.f : 0.f;
      ssv[tid] = vp * (1.f - sp);
      sh[tid] = sp;
    }
    __syncthreads();
    if (tid < 256) AT_ADD(tp + (t % 3) * 256 + tid, sh[tid] + sh[256 + tid]);

    // ===== P7: up = h2@C^T + XD ; LIF2 ; out ; publish top =====
    if (fl) {
      if (tid < 128) {
        int r = tid >> 6, lane = tid & 63;
        int base = 0;
        for (int seg = 0; seg < 4; ++seg) {
          int k = seg * 64 + lane;
          bool p = sh[r * 256 + k] > 0.5f;
          unsigned long long m = __ballot(p);
          int pre = __popcll(m & ((1ull << lane) - 1ull));
          if (p) acts[r * 256 + base + pre] = k;
          base += __popcll(m);
        }
        if (lane == 0) nact2[r] = base;
      }
      __syncthreads();
      {
        int r = tid >> 9, m = tid & 511;
        int grow = bid * 2 + r;
        int n = nact2[r];
        const int* al = acts + r * 256;
        float a0 = 0.f;
        for (int i = 0; i < n; ++i) a0 += Ct[(size_t)al[i] * 512 + m];
        float xd = XD[((size_t)t * 512 + grow) * 512 + m];
        float up = a0 + xd;
        float vp = sov[r * 512 + m] * DECAYF + up;
        float s0 = (vp >= sto[m]) ? 1.f : 0.f;
        sov[r * 512 + m] = vp * (1.f - s0);
        sou[r * 512 + m] = s0;
        int b = grow >> 7, sI = grow & 127;
        out[(((size_t)b * TT + t) * SSS + sI) * DMM + m] = s0;
      }
      __syncthreads();
      if (tid < 512) AT_ADD(top + (t % 3) * 512 + tid, sou[tid] + sou[512 + tid]);
    } else {
      int r = tid >> 9, m = tid & 511;
      int grow = bid * 2 + r;
      int b = grow >> 7, sI = grow & 127;
      out[(((size_t)b * TT + t) * SSS + sI) * DMM + m] = 0.f;
    }

    // ===== ARRIVE =====
    __syncthreads();
    if (tid == 0) {
      asm volatile("s_waitcnt vmcnt(0)" ::: "memory");
      AT_ADD(arr, 1);
    }
  }
}

// ---------------- host ----------------
extern "C" void kernel_launch(void* const* d_in, const int* in_sizes, int n_in,
                              void* d_out, int out_size, void* d_ws, size_t ws_size,
                              hipStream_t stream) {
  const float* x  = (const float*)d_in[0];
  const float* Aw = (const float*)d_in[1];
  const float* Cw = (const float*)d_in[2];
  const float* Dw = (const float*)d_in[3];
  const float* Wq = (const float*)d_in[4];
  const float* bq = (const float*)d_in[5];
  const float* Wk = (const float*)d_in[6];
  const float* bk = (const float*)d_in[7];
  const float* Wv = (const float*)d_in[8];
  const float* bv = (const float*)d_in[9];
  const float* Wo = (const float*)d_in[10];
  const float* bo = (const float*)d_in[11];
  float* ws  = (float*)d_ws;
  float* out = (float*)d_out;

  if (ws_size < WS_FLOATS * sizeof(float)) {
    hipLaunchKernelGGL(zfill_kernel, dim3((out_size + 255) / 256), dim3(256), 0, stream,
                       out, out_size);
    return;
  }

  hipMemsetAsync((void*)(ws + OFS_TP), 0, (WS_FLOATS - OFS_TP) * sizeof(float), stream);
  hipLaunchKernelGGL(flags_kernel, dim3(TT), dim3(256), 0, stream, x, (int*)(ws + OFS_FLAGS));
  hipLaunchKernelGGL(tr_kernel, dim3(320), dim3(256), 0, stream, Aw, Wq, Wo, Cw, ws);
  hipLaunchKernelGGL(pre_kernel, dim3(12288), dim3(256), 0, stream, x, Wk, bk, Wv, bv, Dw, ws);

  void* kargs[] = { (void*)&bq, (void*)&bo, (void*)&ws, (void*)&out };
  hipLaunchCooperativeKernel((void*)seq_kernel, dim3(NBLK), dim3(NTHR), kargs, 0, stream);
}